// Round 5
// baseline (459.141 us; speedup 1.0000x reference)
//
#include <hip/hip_runtime.h>
#include <hip/hip_bf16.h>
#include <math.h>
#include <stdint.h>

#define B_BATCH   1024
#define D_DIM     512
#define C_CLASSES 100000
#define BM        128
#define BN        128
#define BK        64
#define KITERS    (D_DIM / BK)                    // 8
#define MTILES    (B_BATCH / BM)                  // 8
#define NTILES    ((C_CLASSES + BN - 1) / BN)     // 782
#define NGROUPS   98                              // ceil(782/8)
#define GRID_G    (8 * 8 * NGROUPS)               // 6272 blocks (16 early-exit)
#define WBLK      (C_CLASSES / 8)                 // 12500 weight blocks in prep
#define ABLK      (B_BATCH / 8)                   // 128 embed blocks in prep
#define LOG2E     1.44269504088896340736f
#define COSM      0.87758256189037276f            // cos(0.5)
#define SINM      0.47942553860420301f            // sin(0.5)
#define NEG_LOG_EPS 69.07755278982137f            // -ln(1e-30)

typedef short bf16x8 __attribute__((ext_vector_type(8)));
typedef float f32x4  __attribute__((ext_vector_type(4)));

static __device__ __forceinline__ unsigned short f2bf(float f) {
    unsigned int u = __builtin_bit_cast(unsigned int, f);
    u += 0x7fffu + ((u >> 16) & 1u);              // round-to-nearest-even
    return (unsigned short)(u >> 16);
}

static __device__ __forceinline__ unsigned int pk_rne(float lo, float hi) {
    return (unsigned int)f2bf(lo) | ((unsigned int)f2bf(hi) << 16);
}

static __device__ __forceinline__ unsigned int pk_bf16_trunc(float lo, float hi) {
    return __builtin_amdgcn_perm(__builtin_bit_cast(unsigned int, hi),
                                 __builtin_bit_cast(unsigned int, lo),
                                 0x07060302u);
}

// async 16B/lane global -> LDS (LDS dest = wave-uniform base + lane*16)
static __device__ __forceinline__ void gld16(const unsigned short* g, unsigned short* l) {
    __builtin_amdgcn_global_load_lds(
        (const __attribute__((address_space(1))) unsigned int*)g,
        (__attribute__((address_space(3))) unsigned int*)l, 16, 0, 0);
}

// ------------- kernel 1: fused normalize (W rows + E rows) -> bf16 --------
__global__ __launch_bounds__(256) void prep(const float* __restrict__ W,
                                            const float* __restrict__ E,
                                            unsigned short* __restrict__ Wbf,
                                            unsigned short* __restrict__ Abf,
                                            float* __restrict__ out) {
    const int blk  = blockIdx.x;
    const int wave = threadIdx.x >> 6;
    const int lane = threadIdx.x & 63;
    const bool isW = blk < WBLK;
    if (!isW && blk == WBLK && threadIdx.x == 0) *out = 0.f;

    const float* src = isW ? W : E;
    unsigned short* dst = isW ? Wbf : Abf;
    const int r0 = (isW ? blk : blk - WBLK) * 8 + wave * 2;
    const int r1 = r0 + 1;

    const float4* s0 = (const float4*)(src + (size_t)r0 * D_DIM);
    const float4* s1 = (const float4*)(src + (size_t)r1 * D_DIM);
    float4 a0 = s0[2 * lane], a1 = s0[2 * lane + 1];
    float4 b0 = s1[2 * lane], b1 = s1[2 * lane + 1];

    float sa = a0.x*a0.x + a0.y*a0.y + a0.z*a0.z + a0.w*a0.w
             + a1.x*a1.x + a1.y*a1.y + a1.z*a1.z + a1.w*a1.w;
    float sb = b0.x*b0.x + b0.y*b0.y + b0.z*b0.z + b0.w*b0.w
             + b1.x*b1.x + b1.y*b1.y + b1.z*b1.z + b1.w*b1.w;
    #pragma unroll
    for (int off = 1; off < 64; off <<= 1) {
        sa += __shfl_xor(sa, off);
        sb += __shfl_xor(sb, off);
    }
    float ia = rsqrtf(sa), ib = rsqrtf(sb);
    a0.x *= ia; a0.y *= ia; a0.z *= ia; a0.w *= ia;
    a1.x *= ia; a1.y *= ia; a1.z *= ia; a1.w *= ia;
    b0.x *= ib; b0.y *= ib; b0.z *= ib; b0.w *= ib;
    b1.x *= ib; b1.y *= ib; b1.z *= ib; b1.w *= ib;

    uint4 oa, ob;
    if (isW) {   // trunc pack — identical numerics to prior passing rounds
        oa = (uint4){pk_bf16_trunc(a0.x, a0.y), pk_bf16_trunc(a0.z, a0.w),
                     pk_bf16_trunc(a1.x, a1.y), pk_bf16_trunc(a1.z, a1.w)};
        ob = (uint4){pk_bf16_trunc(b0.x, b0.y), pk_bf16_trunc(b0.z, b0.w),
                     pk_bf16_trunc(b1.x, b1.y), pk_bf16_trunc(b1.z, b1.w)};
    } else {     // RNE pack for embeddings
        oa = (uint4){pk_rne(a0.x, a0.y), pk_rne(a0.z, a0.w),
                     pk_rne(a1.x, a1.y), pk_rne(a1.z, a1.w)};
        ob = (uint4){pk_rne(b0.x, b0.y), pk_rne(b0.z, b0.w),
                     pk_rne(b1.x, b1.y), pk_rne(b1.z, b1.w)};
    }
    ((uint4*)(dst + (size_t)r0 * D_DIM))[lane] = oa;
    ((uint4*)(dst + (size_t)r1 * D_DIM))[lane] = ob;
}

// epilogue per-element: clip, ArcFace margin (identity form), returns exp(s-64)
static __device__ __forceinline__ float epi_term(float accv, int col, int lab,
                                                 float* __restrict__ st, int srow) {
    float c = fminf(1.f, fmaxf(-1.f, accv));
    if (col >= C_CLASSES) return 0.f;
    float s = c * 64.0f;
    if (col == lab) {
        float sn = sqrtf(fmaxf(0.f, 1.f - c * c));
        float nm = c * COSM - sn * SINM;          // cos(theta + m)
        if (c < -COSM) nm = -1.f;                 // theta + m > pi
        s = nm * 64.0f;
        st[srow] = s;                             // unique writer across grid
    }
    return exp2f((s - 64.0f) * LOG2E);
}

// ---------------- kernel 2: bf16 GEMM + margin + partial softmax ----------
// Round-1 2-barrier loop (best measured structure), BK 32->64: HALF the
// barrier drains (8 iters), 32 MFMA per drain, still 4 blocks/CU (33 KiB).
// 128B rows would be a 16-way ds_read conflict -> round-2-verified XOR
// swizzle: phys 16B-slot = logical ^ (row&7); gld16 dest stays linear,
// global SOURCE is inverse-swizzled (rule #21), reads apply the same XOR.
// Fragments loaded per-k-half (32 VGPR live) to stay under the 128-reg cap.
// Tripwires: VGPR<=128, WRITE_SIZE ~26MB, SQ_LDS_BANK_CONFLICT ~0, absmax 0.
__global__ __launch_bounds__(256, 4) void gemm_cos(const unsigned short* __restrict__ Abf,
                                                   const unsigned short* __restrict__ Wbf,
                                                   const int* __restrict__ labels,
                                                   float* __restrict__ st,
                                                   float* __restrict__ partial) {
    __shared__ unsigned short As[BM * BK];   // 16 KiB
    __shared__ unsigned short Bs[BN * BK];   // 16 KiB
    __shared__ float rowSum[BM];
    __shared__ int   labs[BM];

    const int id = blockIdx.x;
    const int x  = id & 7;          // XCD slot
    const int s  = id >> 3;         // sequence on this XCD
    const int mt = s & 7;           // m-tile
    const int y  = x + 8 * (s >> 3);// n-tile: 8 consecutive s share y per XCD
    if (y >= NTILES) return;
    const int m0 = mt * BM;
    const int n0 = y * BN;

    const int tid = threadIdx.x;
    if (tid < BM) { labs[tid] = labels[m0 + tid]; rowSum[tid] = 0.f; }

    const int lane = tid & 63;
    const int wave = tid >> 6;
    const int wm = wave & 1, wn = wave >> 1;
    const int l15 = lane & 15, quad = lane >> 4;

    // ---- staging: wave stages chunks 4w..4w+3; chunk = 8 rows x 128B ----
    // gld16 dest linear: lane -> (row=lane>>3, slot=lane&7). Source slot is
    // inverse-swizzled: (lane&7) ^ (row&7).
    const int rIn = lane >> 3;                         // row in chunk 0..7
    const int csl = (((lane & 7) ^ rIn) << 4);         // swizzled src byte off
    const char* gA[4];
    const char* gB[4];
    unsigned short* lA[4];
    unsigned short* lB[4];
    #pragma unroll
    for (int c = 0; c < 4; ++c) {
        const int chunk = wave * 4 + c;
        const int row = chunk * 8 + rIn;
        gA[c] = (const char*)Abf + (size_t)(m0 + row) * (D_DIM * 2) + csl;
        const int bRow = min(n0 + row, C_CLASSES - 1);
        gB[c] = (const char*)Wbf + (size_t)bRow * (D_DIM * 2) + csl;
        lA[c] = &As[chunk * 512];                      // 1 KiB per chunk
        lB[c] = &Bs[chunk * 512];
    }

    const f32x4 z = (f32x4){0.f, 0.f, 0.f, 0.f};
    f32x4 a00 = z, a01 = z, a02 = z, a03 = z;
    f32x4 a10 = z, a11 = z, a12 = z, a13 = z;
    f32x4 a20 = z, a21 = z, a22 = z, a23 = z;
    f32x4 a30 = z, a31 = z, a32 = z, a33 = z;

    // frag read bases: row = (wm|wn)*64 + m*16 + l15, 128B row stride
    const char* baseA = (const char*)As + (size_t)(wm * 64 + l15) * 128;
    const char* baseB = (const char*)Bs + (size_t)(wn * 64 + l15) * 128;
    // swizzled slot: phys_byte = ((kh*4+quad) ^ (l15&7))<<4 == q0 ^ (kh<<6)
    const int q0 = ((quad ^ (l15 & 7)) << 4);

    for (int kk = 0; kk < KITERS; ++kk) {
        __syncthreads();                     // prior frag reads done
        #pragma unroll
        for (int c = 0; c < 4; ++c) {
            gld16((const unsigned short*)gA[c], lA[c]); gA[c] += 2 * BK;
            gld16((const unsigned short*)gB[c], lB[c]); gB[c] += 2 * BK;
        }
        __syncthreads();                     // loads visible (vmcnt drain here)

        #pragma unroll
        for (int kh = 0; kh < 2; ++kh) {
            const int off = q0 ^ (kh << 6);
            bf16x8 af0 = *(const bf16x8*)(baseA          + off);
            bf16x8 af1 = *(const bf16x8*)(baseA + 2048   + off);
            bf16x8 af2 = *(const bf16x8*)(baseA + 4096   + off);
            bf16x8 af3 = *(const bf16x8*)(baseA + 6144   + off);
            bf16x8 bf0 = *(const bf16x8*)(baseB          + off);
            bf16x8 bf1 = *(const bf16x8*)(baseB + 2048   + off);
            bf16x8 bf2 = *(const bf16x8*)(baseB + 4096   + off);
            bf16x8 bf3 = *(const bf16x8*)(baseB + 6144   + off);

            a00 = __builtin_amdgcn_mfma_f32_16x16x32_bf16(af0, bf0, a00, 0, 0, 0);
            a01 = __builtin_amdgcn_mfma_f32_16x16x32_bf16(af0, bf1, a01, 0, 0, 0);
            a02 = __builtin_amdgcn_mfma_f32_16x16x32_bf16(af0, bf2, a02, 0, 0, 0);
            a03 = __builtin_amdgcn_mfma_f32_16x16x32_bf16(af0, bf3, a03, 0, 0, 0);
            a10 = __builtin_amdgcn_mfma_f32_16x16x32_bf16(af1, bf0, a10, 0, 0, 0);
            a11 = __builtin_amdgcn_mfma_f32_16x16x32_bf16(af1, bf1, a11, 0, 0, 0);
            a12 = __builtin_amdgcn_mfma_f32_16x16x32_bf16(af1, bf2, a12, 0, 0, 0);
            a13 = __builtin_amdgcn_mfma_f32_16x16x32_bf16(af1, bf3, a13, 0, 0, 0);
            a20 = __builtin_amdgcn_mfma_f32_16x16x32_bf16(af2, bf0, a20, 0, 0, 0);
            a21 = __builtin_amdgcn_mfma_f32_16x16x32_bf16(af2, bf1, a21, 0, 0, 0);
            a22 = __builtin_amdgcn_mfma_f32_16x16x32_bf16(af2, bf2, a22, 0, 0, 0);
            a23 = __builtin_amdgcn_mfma_f32_16x16x32_bf16(af2, bf3, a23, 0, 0, 0);
            a30 = __builtin_amdgcn_mfma_f32_16x16x32_bf16(af3, bf0, a30, 0, 0, 0);
            a31 = __builtin_amdgcn_mfma_f32_16x16x32_bf16(af3, bf1, a31, 0, 0, 0);
            a32 = __builtin_amdgcn_mfma_f32_16x16x32_bf16(af3, bf2, a32, 0, 0, 0);
            a33 = __builtin_amdgcn_mfma_f32_16x16x32_bf16(af3, bf3, a33, 0, 0, 0);
        }
    }

    const int colbase = n0 + wn * 64 + l15;

    #define EPIROW(A0, A1, A2, A3, MI)                                         \
    {                                                                          \
        _Pragma("unroll")                                                      \
        for (int r = 0; r < 4; ++r) {                                          \
            const int rloc = wm * 64 + (MI) * 16 + quad * 4 + r;               \
            const int lab = labs[rloc];                                        \
            float part = 0.f;                                                  \
            part += epi_term((A0)[r], colbase,      lab, st, m0 + rloc);       \
            part += epi_term((A1)[r], colbase + 16, lab, st, m0 + rloc);       \
            part += epi_term((A2)[r], colbase + 32, lab, st, m0 + rloc);       \
            part += epi_term((A3)[r], colbase + 48, lab, st, m0 + rloc);       \
            part += __shfl_xor(part, 1);                                       \
            part += __shfl_xor(part, 2);                                       \
            part += __shfl_xor(part, 4);                                       \
            part += __shfl_xor(part, 8);                                       \
            if (l15 == 0) atomicAdd(&rowSum[rloc], part);                      \
        }                                                                      \
    }

    EPIROW(a00, a01, a02, a03, 0)
    EPIROW(a10, a11, a12, a13, 1)
    EPIROW(a20, a21, a22, a23, 2)
    EPIROW(a30, a31, a32, a33, 3)
    #undef EPIROW

    __syncthreads();
    // [B][NTILES] layout: reduce_loss reads are lane-contiguous (coalesced).
    if (tid < BM) partial[(size_t)(m0 + tid) * NTILES + y] = rowSum[tid];
}

// ---------------- kernel 3: per-row combine + mean loss ----------------
__global__ __launch_bounds__(64) void reduce_loss(const float* __restrict__ partial,
                                                  const float* __restrict__ st,
                                                  float* __restrict__ out) {
    const int b = blockIdx.x;
    const int l = threadIdx.x;
    const float* row = partial + (size_t)b * NTILES;
    float L = 0.f;
    for (int t = l; t < NTILES; t += 64) L += row[t];   // coalesced across lanes
    #pragma unroll
    for (int off = 1; off < 64; off <<= 1) L += __shfl_xor(L, off);
    if (l == 0) {
        float logp = st[b] - 64.0f - logf(L);
        float lossb = fminf(-logp, NEG_LOG_EPS) * (1.0f / (float)B_BATCH);
        atomicAdd(out, lossb);
    }
}

extern "C" void kernel_launch(void* const* d_in, const int* in_sizes, int n_in,
                              void* d_out, int out_size, void* d_ws, size_t ws_size,
                              hipStream_t stream) {
    const float* emb = (const float*)d_in[0];
    const float* wgt = (const float*)d_in[1];
    const int*   lab = (const int*)d_in[2];
    float* out = (float*)d_out;
    char* ws = (char*)d_ws;

    const size_t WBF_B = (size_t)C_CLASSES * D_DIM * 2;  // 102,400,000
    const size_t ABF_B = (size_t)B_BATCH * D_DIM * 2;    // 1,048,576

    unsigned short* Wbf = (unsigned short*)ws;
    unsigned short* Abf = (unsigned short*)(ws + WBF_B);
    float* st      = (float*)(ws + WBF_B + ABF_B);
    float* partial = (float*)(ws + WBF_B + ABF_B + 4096);

    // 3 dispatches (memset folded into prep, embed+weight fused)
    prep<<<WBLK + ABLK, 256, 0, stream>>>(wgt, emb, Wbf, Abf, out);
    gemm_cos<<<GRID_G, 256, 0, stream>>>(Abf, Wbf, lab, st, partial);
    reduce_loss<<<B_BATCH, 64, 0, stream>>>(partial, st, out);
}

// Round 7
// 451.199 us; speedup vs baseline: 1.0176x; 1.0176x over previous
//
#include <hip/hip_runtime.h>
#include <hip/hip_bf16.h>
#include <math.h>
#include <stdint.h>

#define B_BATCH   1024
#define D_DIM     512
#define C_CLASSES 100000
#define BM        128
#define BN        128
#define BK        32
#define KITERS    (D_DIM / BK)                    // 16
#define MTILES    (B_BATCH / BM)                  // 8
#define NTILES    ((C_CLASSES + BN - 1) / BN)     // 782
#define NGROUPS   98                              // ceil(782/8)
#define GRID_G    (8 * 8 * NGROUPS)               // 6272 blocks (16 early-exit)
#define WBLK      (C_CLASSES / 8)                 // 12500 weight blocks in prep
#define ABLK      (B_BATCH / 8)                   // 128 embed blocks in prep
#define LOG2E     1.44269504088896340736f
#define K64LOG2E  92.33248261689366f              // 64 * log2(e)
#define COSM      0.87758256189037276f            // cos(0.5)
#define SINM      0.47942553860420301f            // sin(0.5)
#define NEG_LOG_EPS 69.07755278982137f            // -ln(1e-30)

typedef short bf16x8 __attribute__((ext_vector_type(8)));
typedef float f32x4  __attribute__((ext_vector_type(4)));

static __device__ __forceinline__ unsigned short f2bf(float f) {
    unsigned int u = __builtin_bit_cast(unsigned int, f);
    u += 0x7fffu + ((u >> 16) & 1u);              // round-to-nearest-even
    return (unsigned short)(u >> 16);
}

static __device__ __forceinline__ unsigned int pk_rne(float lo, float hi) {
    return (unsigned int)f2bf(lo) | ((unsigned int)f2bf(hi) << 16);
}

static __device__ __forceinline__ unsigned int pk_bf16_trunc(float lo, float hi) {
    return __builtin_amdgcn_perm(__builtin_bit_cast(unsigned int, hi),
                                 __builtin_bit_cast(unsigned int, lo),
                                 0x07060302u);
}

// async 16B/lane global -> LDS (LDS dest = wave-uniform base + lane*16)
static __device__ __forceinline__ void gld16(const unsigned short* g, unsigned short* l) {
    __builtin_amdgcn_global_load_lds(
        (const __attribute__((address_space(1))) unsigned int*)g,
        (__attribute__((address_space(3))) unsigned int*)l, 16, 0, 0);
}

// ------------- kernel 1: fused normalize (W rows + E rows) -> bf16 --------
__global__ __launch_bounds__(256) void prep(const float* __restrict__ W,
                                            const float* __restrict__ E,
                                            unsigned short* __restrict__ Wbf,
                                            unsigned short* __restrict__ Abf,
                                            float* __restrict__ out) {
    const int blk  = blockIdx.x;
    const int wave = threadIdx.x >> 6;
    const int lane = threadIdx.x & 63;
    const bool isW = blk < WBLK;
    if (!isW && blk == WBLK && threadIdx.x == 0) *out = 0.f;

    const float* src = isW ? W : E;
    unsigned short* dst = isW ? Wbf : Abf;
    const int r0 = (isW ? blk : blk - WBLK) * 8 + wave * 2;
    const int r1 = r0 + 1;

    const float4* s0 = (const float4*)(src + (size_t)r0 * D_DIM);
    const float4* s1 = (const float4*)(src + (size_t)r1 * D_DIM);
    float4 a0 = s0[2 * lane], a1 = s0[2 * lane + 1];
    float4 b0 = s1[2 * lane], b1 = s1[2 * lane + 1];

    float sa = a0.x*a0.x + a0.y*a0.y + a0.z*a0.z + a0.w*a0.w
             + a1.x*a1.x + a1.y*a1.y + a1.z*a1.z + a1.w*a1.w;
    float sb = b0.x*b0.x + b0.y*b0.y + b0.z*b0.z + b0.w*b0.w
             + b1.x*b1.x + b1.y*b1.y + b1.z*b1.z + b1.w*b1.w;
    #pragma unroll
    for (int off = 1; off < 64; off <<= 1) {
        sa += __shfl_xor(sa, off);
        sb += __shfl_xor(sb, off);
    }
    float ia = rsqrtf(sa), ib = rsqrtf(sb);
    a0.x *= ia; a0.y *= ia; a0.z *= ia; a0.w *= ia;
    a1.x *= ia; a1.y *= ia; a1.z *= ia; a1.w *= ia;
    b0.x *= ib; b0.y *= ib; b0.z *= ib; b0.w *= ib;
    b1.x *= ib; b1.y *= ib; b1.z *= ib; b1.w *= ib;

    uint4 oa, ob;
    if (isW) {   // trunc pack — identical numerics to prior passing rounds
        oa = (uint4){pk_bf16_trunc(a0.x, a0.y), pk_bf16_trunc(a0.z, a0.w),
                     pk_bf16_trunc(a1.x, a1.y), pk_bf16_trunc(a1.z, a1.w)};
        ob = (uint4){pk_bf16_trunc(b0.x, b0.y), pk_bf16_trunc(b0.z, b0.w),
                     pk_bf16_trunc(b1.x, b1.y), pk_bf16_trunc(b1.z, b1.w)};
    } else {     // RNE pack for embeddings
        oa = (uint4){pk_rne(a0.x, a0.y), pk_rne(a0.z, a0.w),
                     pk_rne(a1.x, a1.y), pk_rne(a1.z, a1.w)};
        ob = (uint4){pk_rne(b0.x, b0.y), pk_rne(b0.z, b0.w),
                     pk_rne(b1.x, b1.y), pk_rne(b1.z, b1.w)};
    }
    ((uint4*)(dst + (size_t)r0 * D_DIM))[lane] = oa;
    ((uint4*)(dst + (size_t)r1 * D_DIM))[lane] = ob;
}

// slim epilogue term (calibrated: epilogue was ~28% of CU cycles at 9 VALU
// ops/logit; this is 5). exp(64c-64) = exp2(min(0, fma(c,K,-K))):
//  - upper clip folds into the min (c>=1 -> arg 0 -> term 1, same as clip)
//  - lower clip unnecessary: c<-1 -> arg<-184.6 -> exp2 underflows to 0.0f,
//    equal to the old clipped path's contribution at fp32
//  - OOB col check hoisted to per-block EDGE template
template<bool EDGE>
static __device__ __forceinline__ float epi_term(float accv, int col, int lab,
                                                 float* __restrict__ st, int srow) {
    if (EDGE && col >= C_CLASSES) return 0.f;
    float t = exp2f(fminf(0.f, __builtin_fmaf(accv, K64LOG2E, -K64LOG2E)));
    if (col == lab) {                             // rare: wave-uniformly skipped
        float c = fminf(1.f, fmaxf(-1.f, accv));
        float sn = sqrtf(fmaxf(0.f, 1.f - c * c));
        float nm = c * COSM - sn * SINM;          // cos(theta + m)
        if (c < -COSM) nm = -1.f;                 // theta + m > pi
        float s = nm * 64.0f;
        st[srow] = s;                             // unique writer across grid
        t = exp2f((s - 64.0f) * LOG2E);
    }
    return t;
}

// ---------------- kernel 2: bf16 GEMM + margin + partial softmax ----------
// EXACT round-1/round-4 loop (best measured: ~168 us @ (256,4)). Schedule
// matrix is now fully measured: 2-barrier BK32=168, dbuf-1bar=178, BK64=203,
// 256^2-8ph-drain0=225. The loop stays frozen; PENDING EXPERIMENT (bench
// failed at acquisition): slimmed epilogue (5 VALU/logit vs 9, EDGE split).
__global__ __launch_bounds__(256, 4) void gemm_cos(const unsigned short* __restrict__ Abf,
                                                   const unsigned short* __restrict__ Wbf,
                                                   const int* __restrict__ labels,
                                                   float* __restrict__ st,
                                                   float* __restrict__ partial) {
    __shared__ unsigned short As[BM * BK];   // 8 KiB, unpadded (global_load_lds layout)
    __shared__ unsigned short Bs[BN * BK];   // 8 KiB
    __shared__ float rowSum[BM];
    __shared__ int   labs[BM];

    const int id = blockIdx.x;
    const int x  = id & 7;          // XCD slot
    const int s  = id >> 3;         // sequence on this XCD
    const int mt = s & 7;           // m-tile
    const int y  = x + 8 * (s >> 3);// n-tile: 8 consecutive s share y per XCD
    if (y >= NTILES) return;
    const int m0 = mt * BM;
    const int n0 = y * BN;

    const int tid = threadIdx.x;
    if (tid < BM) { labs[tid] = labels[m0 + tid]; rowSum[tid] = 0.f; }

    const int lane = tid & 63;
    const int wave = tid >> 6;
    const int wm = wave & 1, wn = wave >> 1;
    const int l15 = lane & 15, quad = lane >> 4;

    // staging: wave w stages chunks (2w),(2w+1); chunk c = tile rows [16c,16c+16)
    const int rsub = lane >> 2;
    const int cg   = (lane & 3) * 8;
    const int c0 = wave * 2, c1 = wave * 2 + 1;
    const unsigned short* gA0 = Abf + (size_t)(m0 + c0 * 16 + rsub) * D_DIM + cg;
    const unsigned short* gA1 = Abf + (size_t)(m0 + c1 * 16 + rsub) * D_DIM + cg;
    const int bR0 = min(n0 + c0 * 16 + rsub, C_CLASSES - 1);
    const int bR1 = min(n0 + c1 * 16 + rsub, C_CLASSES - 1);
    const unsigned short* gB0 = Wbf + (size_t)bR0 * D_DIM + cg;
    const unsigned short* gB1 = Wbf + (size_t)bR1 * D_DIM + cg;
    unsigned short* lA0 = &As[c0 * 512];
    unsigned short* lA1 = &As[c1 * 512];
    unsigned short* lB0 = &Bs[c0 * 512];
    unsigned short* lB1 = &Bs[c1 * 512];

    const f32x4 z = (f32x4){0.f, 0.f, 0.f, 0.f};
    f32x4 a00 = z, a01 = z, a02 = z, a03 = z;
    f32x4 a10 = z, a11 = z, a12 = z, a13 = z;
    f32x4 a20 = z, a21 = z, a22 = z, a23 = z;
    f32x4 a30 = z, a31 = z, a32 = z, a33 = z;

    const int aro = (wm * 64 + l15) * BK + quad * 8;
    const int bro = (wn * 64 + l15) * BK + quad * 8;

    for (int kk = 0; kk < KITERS; ++kk) {
        __syncthreads();                     // prior frag reads done
        gld16(gA0, lA0); gld16(gA1, lA1);
        gld16(gB0, lB0); gld16(gB1, lB1);
        gA0 += BK; gA1 += BK; gB0 += BK; gB1 += BK;
        __syncthreads();                     // loads visible

        bf16x8 af0 = *(const bf16x8*)&As[aro];
        bf16x8 af1 = *(const bf16x8*)&As[aro + 16 * BK];
        bf16x8 af2 = *(const bf16x8*)&As[aro + 32 * BK];
        bf16x8 af3 = *(const bf16x8*)&As[aro + 48 * BK];
        bf16x8 bf0 = *(const bf16x8*)&Bs[bro];
        bf16x8 bf1 = *(const bf16x8*)&Bs[bro + 16 * BK];
        bf16x8 bf2 = *(const bf16x8*)&Bs[bro + 32 * BK];
        bf16x8 bf3 = *(const bf16x8*)&Bs[bro + 48 * BK];

        a00 = __builtin_amdgcn_mfma_f32_16x16x32_bf16(af0, bf0, a00, 0, 0, 0);
        a01 = __builtin_amdgcn_mfma_f32_16x16x32_bf16(af0, bf1, a01, 0, 0, 0);
        a02 = __builtin_amdgcn_mfma_f32_16x16x32_bf16(af0, bf2, a02, 0, 0, 0);
        a03 = __builtin_amdgcn_mfma_f32_16x16x32_bf16(af0, bf3, a03, 0, 0, 0);
        a10 = __builtin_amdgcn_mfma_f32_16x16x32_bf16(af1, bf0, a10, 0, 0, 0);
        a11 = __builtin_amdgcn_mfma_f32_16x16x32_bf16(af1, bf1, a11, 0, 0, 0);
        a12 = __builtin_amdgcn_mfma_f32_16x16x32_bf16(af1, bf2, a12, 0, 0, 0);
        a13 = __builtin_amdgcn_mfma_f32_16x16x32_bf16(af1, bf3, a13, 0, 0, 0);
        a20 = __builtin_amdgcn_mfma_f32_16x16x32_bf16(af2, bf0, a20, 0, 0, 0);
        a21 = __builtin_amdgcn_mfma_f32_16x16x32_bf16(af2, bf1, a21, 0, 0, 0);
        a22 = __builtin_amdgcn_mfma_f32_16x16x32_bf16(af2, bf2, a22, 0, 0, 0);
        a23 = __builtin_amdgcn_mfma_f32_16x16x32_bf16(af2, bf3, a23, 0, 0, 0);
        a30 = __builtin_amdgcn_mfma_f32_16x16x32_bf16(af3, bf0, a30, 0, 0, 0);
        a31 = __builtin_amdgcn_mfma_f32_16x16x32_bf16(af3, bf1, a31, 0, 0, 0);
        a32 = __builtin_amdgcn_mfma_f32_16x16x32_bf16(af3, bf2, a32, 0, 0, 0);
        a33 = __builtin_amdgcn_mfma_f32_16x16x32_bf16(af3, bf3, a33, 0, 0, 0);
    }

    const int colbase = n0 + wn * 64 + l15;

    #define EPIROW(EDGE, A0, A1, A2, A3, MI)                                   \
    {                                                                          \
        _Pragma("unroll")                                                      \
        for (int r = 0; r < 4; ++r) {                                          \
            const int rloc = wm * 64 + (MI) * 16 + quad * 4 + r;               \
            const int lab = labs[rloc];                                        \
            float part = 0.f;                                                  \
            part += epi_term<EDGE>((A0)[r], colbase,      lab, st, m0 + rloc); \
            part += epi_term<EDGE>((A1)[r], colbase + 16, lab, st, m0 + rloc); \
            part += epi_term<EDGE>((A2)[r], colbase + 32, lab, st, m0 + rloc); \
            part += epi_term<EDGE>((A3)[r], colbase + 48, lab, st, m0 + rloc); \
            part += __shfl_xor(part, 1);                                       \
            part += __shfl_xor(part, 2);                                       \
            part += __shfl_xor(part, 4);                                       \
            part += __shfl_xor(part, 8);                                       \
            if (l15 == 0) atomicAdd(&rowSum[rloc], part);                      \
        }                                                                      \
    }

    if (n0 + BN <= C_CLASSES) {        // fast path: no OOB columns (y < 781)
        EPIROW(false, a00, a01, a02, a03, 0)
        EPIROW(false, a10, a11, a12, a13, 1)
        EPIROW(false, a20, a21, a22, a23, 2)
        EPIROW(false, a30, a31, a32, a33, 3)
    } else {                           // edge tile: per-element OOB check
        EPIROW(true,  a00, a01, a02, a03, 0)
        EPIROW(true,  a10, a11, a12, a13, 1)
        EPIROW(true,  a20, a21, a22, a23, 2)
        EPIROW(true,  a30, a31, a32, a33, 3)
    }
    #undef EPIROW

    __syncthreads();
    // [B][NTILES] layout: reduce_loss reads are lane-contiguous (coalesced).
    if (tid < BM) partial[(size_t)(m0 + tid) * NTILES + y] = rowSum[tid];
}

// ---------------- kernel 3: per-row combine + mean loss ----------------
__global__ __launch_bounds__(64) void reduce_loss(const float* __restrict__ partial,
                                                  const float* __restrict__ st,
                                                  float* __restrict__ out) {
    const int b = blockIdx.x;
    const int l = threadIdx.x;
    const float* row = partial + (size_t)b * NTILES;
    float L = 0.f;
    for (int t = l; t < NTILES; t += 64) L += row[t];   // coalesced across lanes
    #pragma unroll
    for (int off = 1; off < 64; off <<= 1) L += __shfl_xor(L, off);
    if (l == 0) {
        float logp = st[b] - 64.0f - logf(L);
        float lossb = fminf(-logp, NEG_LOG_EPS) * (1.0f / (float)B_BATCH);
        atomicAdd(out, lossb);
    }
}

extern "C" void kernel_launch(void* const* d_in, const int* in_sizes, int n_in,
                              void* d_out, int out_size, void* d_ws, size_t ws_size,
                              hipStream_t stream) {
    const float* emb = (const float*)d_in[0];
    const float* wgt = (const float*)d_in[1];
    const int*   lab = (const int*)d_in[2];
    float* out = (float*)d_out;
    char* ws = (char*)d_ws;

    const size_t WBF_B = (size_t)C_CLASSES * D_DIM * 2;  // 102,400,000
    const size_t ABF_B = (size_t)B_BATCH * D_DIM * 2;    // 1,048,576

    unsigned short* Wbf = (unsigned short*)ws;
    unsigned short* Abf = (unsigned short*)(ws + WBF_B);
    float* st      = (float*)(ws + WBF_B + ABF_B);
    float* partial = (float*)(ws + WBF_B + ABF_B + 4096);

    // 3 dispatches (memset folded into prep, embed+weight fused)
    prep<<<WBLK + ABLK, 256, 0, stream>>>(wgt, emb, Wbf, Abf, out);
    gemm_cos<<<GRID_G, 256, 0, stream>>>(Abf, Wbf, lab, st, partial);
    reduce_loss<<<B_BATCH, 64, 0, stream>>>(partial, st, out);
}